// Round 8
// baseline (118.569 us; speedup 1.0000x reference)
//
#include <hip/hip_runtime.h>
#include <cmath>

namespace {

typedef __attribute__((ext_vector_type(8))) short short8;
typedef __attribute__((ext_vector_type(4))) float f32x4;
typedef __attribute__((ext_vector_type(4))) unsigned u32x4;

constexpr float kScale = 0.08838834764831845f;  // 128^-0.5

__device__ __forceinline__ int voxel_row(int p, int pix) {
  int pd = p >> 6, ph = (p >> 3) & 7, pw = p & 7;
  int iz = pix >> 4, iy = (pix >> 2) & 3, ix = pix & 3;
  return (((pd * 4 + iz) * 32 + (ph * 4 + iy)) * 32 + (pw * 4 + ix));
}

__device__ __forceinline__ float dot4(float4 a, float4 b) {
  return a.x * b.x + a.y * b.y + a.z * b.z + a.w * b.w;
}

__device__ __forceinline__ short bf16c(float f) {
  unsigned u = __builtin_bit_cast(unsigned, f);
  u += 0x7fffu + ((u >> 16) & 1u);
  return (short)(u >> 16);
}

__device__ __forceinline__ unsigned bfpack(float lo, float hi) {
  return (unsigned)(unsigned short)bf16c(lo) |
         ((unsigned)(unsigned short)bf16c(hi) << 16);
}

__device__ __forceinline__ short8 cvt8(const float* src) {
  float4 a = *(const float4*)src, b = *(const float4*)(src + 4);
  short8 o;
  o[0] = bf16c(a.x); o[1] = bf16c(a.y); o[2] = bf16c(a.z); o[3] = bf16c(a.w);
  o[4] = bf16c(b.x); o[5] = bf16c(b.y); o[6] = bf16c(b.z); o[7] = bf16c(b.w);
  return o;
}

__device__ __forceinline__ short8 cvt8s(const float* src, float sc) {
  float4 a = *(const float4*)src, b = *(const float4*)(src + 4);
  short8 o;
  o[0] = bf16c(a.x * sc); o[1] = bf16c(a.y * sc);
  o[2] = bf16c(a.z * sc); o[3] = bf16c(a.w * sc);
  o[4] = bf16c(b.x * sc); o[5] = bf16c(b.y * sc);
  o[6] = bf16c(b.z * sc); o[7] = bf16c(b.w * sc);
  return o;
}

// ---- pack weight (K=128 x N) into per-lane MFMA B-fragments ----
__global__ __launch_bounds__(64) void k_pack(
    const float* __restrict__ w, short* __restrict__ dst, int N) {
  const int lane = threadIdx.x;
  const int ntile = blockIdx.x >> 2, ks = blockIdx.x & 3;
  const int k0 = ks * 32 + (lane >> 4) * 8, col = ntile * 16 + (lane & 15);
  short8 o;
#pragma unroll
  for (int i = 0; i < 8; ++i) o[i] = bf16c(w[(size_t)(k0 + i) * N + col]);
  *(short8*)(dst + ((size_t)blockIdx.x * 64 + lane) * 8) = o;
}

// ---- QKV projection, MFMA; emits q/k/v f32, vt (V^T bf16), kb (K bf16),
// and fused exact-f32 window means -> qwin/kwin (routing inputs) ----
__global__ __launch_bounds__(256) void k_qkv(
    const float* __restrict__ x, const short* __restrict__ wpk,
    const float* __restrict__ bias, const float* __restrict__ wfull,
    float* __restrict__ q, float* __restrict__ k, float* __restrict__ v,
    short* __restrict__ vt, short* __restrict__ kb,
    float* __restrict__ qwin, float* __restrict__ kwin) {
  __shared__ short sX[64][136];
  __shared__ float xpart[16][16][8];
  __shared__ float xm[128];
  const int p = blockIdx.x, t = threadIdx.x;
  const int wave = t >> 6, lane = t & 63, l15 = lane & 15, lg = lane >> 4;

  float ps[8] = {0.f, 0.f, 0.f, 0.f, 0.f, 0.f, 0.f, 0.f};
#pragma unroll
  for (int r = 0; r < 4; ++r) {
    int unit = t + r * 256;
    int row = unit >> 4, u = unit & 15;  // u == t&15 for all r
    const float* src = x + (size_t)voxel_row(p, row) * 128 + u * 8;
    float4 a = *(const float4*)src, b = *(const float4*)(src + 4);
    ps[0] += a.x; ps[1] += a.y; ps[2] += a.z; ps[3] += a.w;
    ps[4] += b.x; ps[5] += b.y; ps[6] += b.z; ps[7] += b.w;
    short8 o;
    o[0] = bf16c(a.x); o[1] = bf16c(a.y); o[2] = bf16c(a.z); o[3] = bf16c(a.w);
    o[4] = bf16c(b.x); o[5] = bf16c(b.y); o[6] = bf16c(b.z); o[7] = bf16c(b.w);
    *(short8*)(&sX[row][u * 8]) = o;
  }
#pragma unroll
  for (int i = 0; i < 8; ++i) xpart[t >> 4][t & 15][i] = ps[i];
  __syncthreads();
  if (t < 128) {
    float s = 0.f;
#pragma unroll
    for (int g = 0; g < 16; ++g) s += xpart[g][t >> 3][t & 7];
    xm[t] = s * (1.f / 64.f);
  }
  __syncthreads();

  f32x4 acc[4][6];
#pragma unroll
  for (int mt = 0; mt < 4; ++mt)
#pragma unroll
    for (int nt = 0; nt < 6; ++nt) acc[mt][nt] = f32x4{0.f, 0.f, 0.f, 0.f};
#pragma unroll
  for (int ks = 0; ks < 4; ++ks) {
    short8 a[4];
#pragma unroll
    for (int mt = 0; mt < 4; ++mt)
      a[mt] = *(const short8*)(&sX[mt * 16 + l15][ks * 32 + lg * 8]);
#pragma unroll
    for (int nt = 0; nt < 6; ++nt) {
      int ntg = wave * 6 + nt;
      short8 b = *(const short8*)(wpk + ((size_t)(ntg * 4 + ks) * 64 + lane) * 8);
#pragma unroll
      for (int mt = 0; mt < 4; ++mt)
        acc[mt][nt] = __builtin_amdgcn_mfma_f32_16x16x32_bf16(a[mt], b, acc[mt][nt], 0, 0, 0);
    }
  }
#pragma unroll
  for (int nt = 0; nt < 6; ++nt) {
    int n = (wave * 6 + nt) * 16 + l15;
    float bv = bias[n];
    float* dst = n < 128 ? q : (n < 256 ? k : v);
    int col = n & 127;
#pragma unroll
    for (int mt = 0; mt < 4; ++mt) {
      float o0 = acc[mt][nt][0] + bv, o1 = acc[mt][nt][1] + bv;
      float o2 = acc[mt][nt][2] + bv, o3 = acc[mt][nt][3] + bv;
      int row0 = mt * 16 + lg * 4;
      dst[(size_t)(p * 64 + row0 + 0) * 128 + col] = o0;
      dst[(size_t)(p * 64 + row0 + 1) * 128 + col] = o1;
      dst[(size_t)(p * 64 + row0 + 2) * 128 + col] = o2;
      dst[(size_t)(p * 64 + row0 + 3) * 128 + col] = o3;
      if (n >= 256) {  // V^T bf16: vt[p][dim][key]
        uint2 pk;
        pk.x = bfpack(o0, o1);
        pk.y = bfpack(o2, o3);
        *(uint2*)(vt + (size_t)p * 8192 + (size_t)(n - 256) * 64 + row0) = pk;
      } else if (n >= 128) {  // K bf16: kb[p*64+key][dim]
        kb[(size_t)(p * 64 + row0 + 0) * 128 + col] = bf16c(o0);
        kb[(size_t)(p * 64 + row0 + 1) * 128 + col] = bf16c(o1);
        kb[(size_t)(p * 64 + row0 + 2) * 128 + col] = bf16c(o2);
        kb[(size_t)(p * 64 + row0 + 3) * 128 + col] = bf16c(o3);
      }
    }
  }

  // fused window-mean projection (exact f32): win = mean(x) @ W_qk + b
  {
    float acc2 = bias[t];
    for (int kk = 0; kk < 128; ++kk)
      acc2 = fmaf(xm[kk], wfull[(size_t)kk * 384 + t], acc2);
    if (t < 128) qwin[p * 128 + t] = acc2;
    else kwin[p * 128 + (t - 128)] = acc2;
  }
}

// ---------------- routing (unchanged) ----------------
__global__ __launch_bounds__(256) void k_route(
    const float* __restrict__ qwin, const float* __restrict__ kwin,
    int* __restrict__ ridx) {
  __shared__ float qs[128];
  __shared__ float lg[512];
  __shared__ float rv[256];
  __shared__ int ri[256];
  const int p = blockIdx.x, t = threadIdx.x;
  if (t < 32) *(float4*)(&qs[t * 4]) = *(const float4*)(qwin + p * 128 + t * 4);
  __syncthreads();
  for (int jj = t; jj < 512; jj += 256) {
    const float* kr = kwin + (size_t)jj * 128;
    float s = 0.f;
    for (int c = 0; c < 128; c += 4) {
      float4 k4 = *(const float4*)(kr + c);
      float4 q4 = *(const float4*)(qs + c);
      s += dot4(q4, k4);
    }
    lg[jj] = s;
  }
  __syncthreads();
  for (int sel = 0; sel < 4; ++sel) {
    float bv = lg[t];
    int bi = t;
    float v2 = lg[t + 256];
    if (v2 > bv) { bv = v2; bi = t + 256; }
    rv[t] = bv; ri[t] = bi;
    __syncthreads();
    for (int off = 128; off > 0; off >>= 1) {
      if (t < off && rv[t + off] > rv[t]) { rv[t] = rv[t + off]; ri[t] = ri[t + off]; }
      __syncthreads();
    }
    if (t == 0) { ridx[p * 4 + sel] = ri[0]; lg[ri[0]] = -INFINITY; }
    __syncthreads();
  }
}

// ---- MFMA attention v3: swapped PV (O^T = V^T P^T), zero LDS ----
// wave = (head, q-half of 32 rows). P^T B-frags built in-register via shfl.
__global__ __launch_bounds__(256, 8) void k_attn(
    const float* __restrict__ q, const short* __restrict__ kb,
    const short* __restrict__ vt, const int* __restrict__ ridx,
    float* __restrict__ ao) {
  const int bid = blockIdx.x, t = threadIdx.x;
  const int p = bid >> 2, quad = bid & 3;
  const int wave = t >> 6, lane = t & 63;
  const int l15 = lane & 15, lg = lane >> 4;
  const int sub = quad * 4 + wave;
  const int h = sub >> 1, qhalf = sub & 1;

  const int4 ws4 = *(const int4*)(ridx + p * 4);
  const int wsa[4] = {ws4.x, ws4.y, ws4.z, ws4.w};

  const int src0 = ((lg & 1) << 5) | l15;  // lane of lg'=(lg&1)*2
  const int src1 = src0 + 16;              // lane of lg'=(lg&1)*2+1

  float m_r[2] = {-1e30f, -1e30f};
  float l_r[2] = {0.f, 0.f};
  f32x4 oacc[2];
  oacc[0] = f32x4{0.f, 0.f, 0.f, 0.f};
  oacc[1] = f32x4{0.f, 0.f, 0.f, 0.f};

#pragma unroll
  for (int c = 0; c < 4; ++c) {
    const int wsel = wsa[c];
    // K A-frags from kb (row=key=l15-group, k=dim, zero-pad dims>=16)
    short8 af[4];
#pragma unroll
    for (int mt = 0; mt < 4; ++mt) {
      if (lg < 2)
        af[mt] = *(const short8*)(kb + ((size_t)(wsel * 64 + mt * 16 + l15)) * 128 + h * 16 + lg * 8);
      else
        af[mt] = short8{0, 0, 0, 0, 0, 0, 0, 0};
    }
    // V^T A-frags (row=dim=l15, k=key) — contiguous in vt
    const short* vw = vt + (size_t)wsel * 8192 + (size_t)(h * 16 + l15) * 64 + lg * 8;
    short8 av0 = *(const short8*)(vw);
    short8 av1 = *(const short8*)(vw + 32);

#pragma unroll
    for (int nt = 0; nt < 2; ++nt) {
      // Q B-frag (col=q=l15, k=dim, zero-pad)
      short8 qf;
      if (lg < 2)
        qf = cvt8s(q + ((size_t)(p * 64 + qhalf * 32 + nt * 16 + l15)) * 128 + h * 16 + lg * 8, kScale);
      else
        qf = short8{0, 0, 0, 0, 0, 0, 0, 0};
      // S^T = K·Q^T: col=l15=q, row=lg*4+j=key mt*16+lg*4+j
      f32x4 s[4];
#pragma unroll
      for (int mt = 0; mt < 4; ++mt)
        s[mt] = __builtin_amdgcn_mfma_f32_16x16x32_bf16(
            af[mt], qf, f32x4{0.f, 0.f, 0.f, 0.f}, 0, 0, 0);
      // online softmax (per-lane q = l15)
      float mx = -1e30f;
#pragma unroll
      for (int mt = 0; mt < 4; ++mt)
#pragma unroll
        for (int j = 0; j < 4; ++j) mx = fmaxf(mx, s[mt][j]);
      mx = fmaxf(mx, __shfl_xor(mx, 16));
      mx = fmaxf(mx, __shfl_xor(mx, 32));
      float mnew = fmaxf(m_r[nt], mx);
      float sc = __expf(m_r[nt] - mnew);
      m_r[nt] = mnew;
      float ls = 0.f;
#pragma unroll
      for (int mt = 0; mt < 4; ++mt)
#pragma unroll
        for (int j = 0; j < 4; ++j) {
          float e = __expf(s[mt][j] - mnew);
          s[mt][j] = e;
          ls += e;
        }
      ls += __shfl_xor(ls, 16);
      ls += __shfl_xor(ls, 32);
      l_r[nt] = l_r[nt] * sc + ls;
      oacc[nt][0] *= sc; oacc[nt][1] *= sc;
      oacc[nt][2] *= sc; oacc[nt][3] *= sc;
      // pack P bf16 pairs: P2[mt][w] = keys mt*16+lg*4+{2w,2w+1} for q=l15
      unsigned P2[4][2];
#pragma unroll
      for (int mt = 0; mt < 4; ++mt) {
        P2[mt][0] = bfpack(s[mt][0], s[mt][1]);
        P2[mt][1] = bfpack(s[mt][2], s[mt][3]);
      }
      // P^T B-frags via shfl: dest lane needs keys lg*8..+7 (kt half)
#pragma unroll
      for (int kt = 0; kt < 2; ++kt) {
        unsigned lo0 = (unsigned)__shfl((int)P2[2 * kt + 0][0], src0);
        unsigned hi0 = (unsigned)__shfl((int)P2[2 * kt + 1][0], src0);
        unsigned lo1 = (unsigned)__shfl((int)P2[2 * kt + 0][1], src0);
        unsigned hi1 = (unsigned)__shfl((int)P2[2 * kt + 1][1], src0);
        unsigned lo2 = (unsigned)__shfl((int)P2[2 * kt + 0][0], src1);
        unsigned hi2 = (unsigned)__shfl((int)P2[2 * kt + 1][0], src1);
        unsigned lo3 = (unsigned)__shfl((int)P2[2 * kt + 0][1], src1);
        unsigned hi3 = (unsigned)__shfl((int)P2[2 * kt + 1][1], src1);
        u32x4 bw;
        bw[0] = (lg < 2) ? lo0 : hi0;
        bw[1] = (lg < 2) ? lo1 : hi1;
        bw[2] = (lg < 2) ? lo2 : hi2;
        bw[3] = (lg < 2) ? lo3 : hi3;
        short8 bfr = __builtin_bit_cast(short8, bw);
        oacc[nt] = __builtin_amdgcn_mfma_f32_16x16x32_bf16(
            kt == 0 ? av0 : av1, bfr, oacc[nt], 0, 0, 0);
      }
    }
  }

  // epilogue: O^T frag -> lane owns q=l15, dims lg*4+j contiguous float4
#pragma unroll
  for (int nt = 0; nt < 2; ++nt) {
    float inv = 1.f / l_r[nt];
    float4 st;
    st.x = oacc[nt][0] * inv; st.y = oacc[nt][1] * inv;
    st.z = oacc[nt][2] * inv; st.w = oacc[nt][3] * inv;
    int qpix = qhalf * 32 + nt * 16 + l15;
    *(float4*)(ao + (size_t)voxel_row(p, qpix) * 128 + h * 16 + lg * 4) = st;
  }
}

// ---- output projection, MFMA, in-place (unchanged) ----
__global__ __launch_bounds__(256) void k_proj(
    float* io, const short* __restrict__ wpk, const float* __restrict__ bias) {
  __shared__ short sX[64][136];
  const int p = blockIdx.x, t = threadIdx.x;
  const int wave = t >> 6, lane = t & 63, l15 = lane & 15, lg = lane >> 4;
#pragma unroll
  for (int r = 0; r < 4; ++r) {
    int unit = t + r * 256;
    int row = unit >> 4, u = unit & 15;
    *(short8*)(&sX[row][u * 8]) =
        cvt8(io + (size_t)voxel_row(p, row) * 128 + u * 8);
  }
  __syncthreads();
  f32x4 acc[4][2];
#pragma unroll
  for (int mt = 0; mt < 4; ++mt) {
    acc[mt][0] = f32x4{0.f, 0.f, 0.f, 0.f};
    acc[mt][1] = f32x4{0.f, 0.f, 0.f, 0.f};
  }
#pragma unroll
  for (int ks = 0; ks < 4; ++ks) {
    short8 a[4];
#pragma unroll
    for (int mt = 0; mt < 4; ++mt)
      a[mt] = *(const short8*)(&sX[mt * 16 + l15][ks * 32 + lg * 8]);
#pragma unroll
    for (int nt = 0; nt < 2; ++nt) {
      int ntg = wave * 2 + nt;
      short8 b = *(const short8*)(wpk + ((size_t)(ntg * 4 + ks) * 64 + lane) * 8);
#pragma unroll
      for (int mt = 0; mt < 4; ++mt)
        acc[mt][nt] = __builtin_amdgcn_mfma_f32_16x16x32_bf16(a[mt], b, acc[mt][nt], 0, 0, 0);
    }
  }
#pragma unroll
  for (int nt = 0; nt < 2; ++nt) {
    int n = (wave * 2 + nt) * 16 + l15;
    float bv = bias[n];
#pragma unroll
    for (int mt = 0; mt < 4; ++mt)
#pragma unroll
      for (int j = 0; j < 4; ++j)
        io[(size_t)voxel_row(p, mt * 16 + lg * 4 + j) * 128 + n] = acc[mt][nt][j] + bv;
  }
}

}  // namespace

extern "C" void kernel_launch(void* const* d_in, const int* in_sizes, int n_in,
                              void* d_out, int out_size, void* d_ws, size_t ws_size,
                              hipStream_t stream) {
  (void)in_sizes; (void)n_in; (void)out_size; (void)ws_size;
  const float* x = (const float*)d_in[0];
  const float* w_qkv = (const float*)d_in[1];
  const float* b_qkv = (const float*)d_in[2];
  const float* w_o = (const float*)d_in[3];
  const float* b_o = (const float*)d_in[4];

  float* out = (float*)d_out;
  float* q = out + 4194304;
  float* k = q + 4194304;
  float* v = k + 4194304;

  float* qwin = (float*)d_ws;                 // 512*128 f32
  float* kwin = qwin + 65536;                 // 512*128 f32
  int* ridx = (int*)(kwin + 65536);           // 512*4 i32
  short* wpk_qkv = (short*)(ridx + 2048);     // 96 KB
  short* wpk_o = wpk_qkv + 49152;             // 32 KB
  short* vt = wpk_o + 16384;                  // 512*128*64 bf16 = 8 MB
  short* kb = vt + 4194304;                   // 512*64*128 bf16 = 8 MB

  k_pack<<<96, 64, 0, stream>>>(w_qkv, wpk_qkv, 384);
  k_pack<<<32, 64, 0, stream>>>(w_o, wpk_o, 128);
  k_qkv<<<512, 256, 0, stream>>>(x, wpk_qkv, b_qkv, w_qkv, q, k, v, vt, kb, qwin, kwin);
  k_route<<<512, 256, 0, stream>>>(qwin, kwin, ridx);
  k_attn<<<2048, 256, 0, stream>>>(q, kb, vt, ridx, out);
  k_proj<<<512, 256, 0, stream>>>(out, wpk_o, b_o);
}

// Round 9
// 88.215 us; speedup vs baseline: 1.3441x; 1.3441x over previous
//
#include <hip/hip_runtime.h>
#include <cmath>

namespace {

typedef __attribute__((ext_vector_type(8))) short short8;
typedef __attribute__((ext_vector_type(4))) float f32x4;
typedef __attribute__((ext_vector_type(4))) unsigned u32x4;

constexpr float kScale = 0.08838834764831845f;  // 128^-0.5

__device__ __forceinline__ int voxel_row(int p, int pix) {
  int pd = p >> 6, ph = (p >> 3) & 7, pw = p & 7;
  int iz = pix >> 4, iy = (pix >> 2) & 3, ix = pix & 3;
  return (((pd * 4 + iz) * 32 + (ph * 4 + iy)) * 32 + (pw * 4 + ix));
}

__device__ __forceinline__ float dot4(float4 a, float4 b) {
  return a.x * b.x + a.y * b.y + a.z * b.z + a.w * b.w;
}

__device__ __forceinline__ short bf16c(float f) {
  unsigned u = __builtin_bit_cast(unsigned, f);
  u += 0x7fffu + ((u >> 16) & 1u);
  return (short)(u >> 16);
}

__device__ __forceinline__ unsigned bfpack(float lo, float hi) {
  return (unsigned)(unsigned short)bf16c(lo) |
         ((unsigned)(unsigned short)bf16c(hi) << 16);
}

__device__ __forceinline__ short8 cvt8(const float* src) {
  float4 a = *(const float4*)src, b = *(const float4*)(src + 4);
  short8 o;
  o[0] = bf16c(a.x); o[1] = bf16c(a.y); o[2] = bf16c(a.z); o[3] = bf16c(a.w);
  o[4] = bf16c(b.x); o[5] = bf16c(b.y); o[6] = bf16c(b.z); o[7] = bf16c(b.w);
  return o;
}

__device__ __forceinline__ short8 cvt8s(const float* src, float sc) {
  float4 a = *(const float4*)src, b = *(const float4*)(src + 4);
  short8 o;
  o[0] = bf16c(a.x * sc); o[1] = bf16c(a.y * sc);
  o[2] = bf16c(a.z * sc); o[3] = bf16c(a.w * sc);
  o[4] = bf16c(b.x * sc); o[5] = bf16c(b.y * sc);
  o[6] = bf16c(b.z * sc); o[7] = bf16c(b.w * sc);
  return o;
}

// ---- pack weight (K=128 x N) into per-lane MFMA B-fragments ----
__global__ __launch_bounds__(64) void k_pack(
    const float* __restrict__ w, short* __restrict__ dst, int N) {
  const int lane = threadIdx.x;
  const int ntile = blockIdx.x >> 2, ks = blockIdx.x & 3;
  const int k0 = ks * 32 + (lane >> 4) * 8, col = ntile * 16 + (lane & 15);
  short8 o;
#pragma unroll
  for (int i = 0; i < 8; ++i) o[i] = bf16c(w[(size_t)(k0 + i) * N + col]);
  *(short8*)(dst + ((size_t)blockIdx.x * 64 + lane) * 8) = o;
}

// ---- QKV projection, MFMA; emits q/k/v f32, vt (V^T bf16, head-contig),
// kbh (K bf16 head-major), and fused exact-f32 window means ----
__global__ __launch_bounds__(256) void k_qkv(
    const float* __restrict__ x, const short* __restrict__ wpk,
    const float* __restrict__ bias, const float* __restrict__ wfull,
    float* __restrict__ q, float* __restrict__ k, float* __restrict__ v,
    short* __restrict__ vt, short* __restrict__ kbh,
    float* __restrict__ qwin, float* __restrict__ kwin) {
  __shared__ short sX[64][136];
  __shared__ float xpart[16][16][8];
  __shared__ float xm[128];
  const int p = blockIdx.x, t = threadIdx.x;
  const int wave = t >> 6, lane = t & 63, l15 = lane & 15, lg = lane >> 4;

  float ps[8] = {0.f, 0.f, 0.f, 0.f, 0.f, 0.f, 0.f, 0.f};
#pragma unroll
  for (int r = 0; r < 4; ++r) {
    int unit = t + r * 256;
    int row = unit >> 4, u = unit & 15;
    const float* src = x + (size_t)voxel_row(p, row) * 128 + u * 8;
    float4 a = *(const float4*)src, b = *(const float4*)(src + 4);
    ps[0] += a.x; ps[1] += a.y; ps[2] += a.z; ps[3] += a.w;
    ps[4] += b.x; ps[5] += b.y; ps[6] += b.z; ps[7] += b.w;
    short8 o;
    o[0] = bf16c(a.x); o[1] = bf16c(a.y); o[2] = bf16c(a.z); o[3] = bf16c(a.w);
    o[4] = bf16c(b.x); o[5] = bf16c(b.y); o[6] = bf16c(b.z); o[7] = bf16c(b.w);
    *(short8*)(&sX[row][u * 8]) = o;
  }
#pragma unroll
  for (int i = 0; i < 8; ++i) xpart[t >> 4][t & 15][i] = ps[i];
  __syncthreads();
  if (t < 128) {
    float s = 0.f;
#pragma unroll
    for (int g = 0; g < 16; ++g) s += xpart[g][t >> 3][t & 7];
    xm[t] = s * (1.f / 64.f);
  }
  __syncthreads();

  f32x4 acc[4][6];
#pragma unroll
  for (int mt = 0; mt < 4; ++mt)
#pragma unroll
    for (int nt = 0; nt < 6; ++nt) acc[mt][nt] = f32x4{0.f, 0.f, 0.f, 0.f};
#pragma unroll
  for (int ks = 0; ks < 4; ++ks) {
    short8 a[4];
#pragma unroll
    for (int mt = 0; mt < 4; ++mt)
      a[mt] = *(const short8*)(&sX[mt * 16 + l15][ks * 32 + lg * 8]);
#pragma unroll
    for (int nt = 0; nt < 6; ++nt) {
      int ntg = wave * 6 + nt;
      short8 b = *(const short8*)(wpk + ((size_t)(ntg * 4 + ks) * 64 + lane) * 8);
#pragma unroll
      for (int mt = 0; mt < 4; ++mt)
        acc[mt][nt] = __builtin_amdgcn_mfma_f32_16x16x32_bf16(a[mt], b, acc[mt][nt], 0, 0, 0);
    }
  }
#pragma unroll
  for (int nt = 0; nt < 6; ++nt) {
    int n = (wave * 6 + nt) * 16 + l15;
    float bv = bias[n];
    float* dst = n < 128 ? q : (n < 256 ? k : v);
    int col = n & 127;
#pragma unroll
    for (int mt = 0; mt < 4; ++mt) {
      float o0 = acc[mt][nt][0] + bv, o1 = acc[mt][nt][1] + bv;
      float o2 = acc[mt][nt][2] + bv, o3 = acc[mt][nt][3] + bv;
      int row0 = mt * 16 + lg * 4;
      dst[(size_t)(p * 64 + row0 + 0) * 128 + col] = o0;
      dst[(size_t)(p * 64 + row0 + 1) * 128 + col] = o1;
      dst[(size_t)(p * 64 + row0 + 2) * 128 + col] = o2;
      dst[(size_t)(p * 64 + row0 + 3) * 128 + col] = o3;
      if (n >= 256) {  // V^T bf16: vt[p][dim][key] (head-contiguous)
        uint2 pk;
        pk.x = bfpack(o0, o1);
        pk.y = bfpack(o2, o3);
        *(uint2*)(vt + (size_t)p * 8192 + (size_t)(n - 256) * 64 + row0) = pk;
      } else if (n >= 128) {  // K bf16 head-major: kbh[p][h][key][16]
        int hh = (n - 128) >> 4, d = (n - 128) & 15;
        short* kd = kbh + (((size_t)(p * 8 + hh)) * 64 + row0) * 16 + d;
        kd[0] = bf16c(o0);
        kd[16] = bf16c(o1);
        kd[32] = bf16c(o2);
        kd[48] = bf16c(o3);
      }
    }
  }

  // fused window-mean projection (exact f32): win = mean(x) @ W_qk + b
  {
    float acc2 = bias[t];
    for (int kk = 0; kk < 128; ++kk)
      acc2 = fmaf(xm[kk], wfull[(size_t)kk * 384 + t], acc2);
    if (t < 128) qwin[p * 128 + t] = acc2;
    else kwin[p * 128 + (t - 128)] = acc2;
  }
}

// ---------------- routing (unchanged) ----------------
__global__ __launch_bounds__(256) void k_route(
    const float* __restrict__ qwin, const float* __restrict__ kwin,
    int* __restrict__ ridx) {
  __shared__ float qs[128];
  __shared__ float lg[512];
  __shared__ float rv[256];
  __shared__ int ri[256];
  const int p = blockIdx.x, t = threadIdx.x;
  if (t < 32) *(float4*)(&qs[t * 4]) = *(const float4*)(qwin + p * 128 + t * 4);
  __syncthreads();
  for (int jj = t; jj < 512; jj += 256) {
    const float* kr = kwin + (size_t)jj * 128;
    float s = 0.f;
    for (int c = 0; c < 128; c += 4) {
      float4 k4 = *(const float4*)(kr + c);
      float4 q4 = *(const float4*)(qs + c);
      s += dot4(q4, k4);
    }
    lg[jj] = s;
  }
  __syncthreads();
  for (int sel = 0; sel < 4; ++sel) {
    float bv = lg[t];
    int bi = t;
    float v2 = lg[t + 256];
    if (v2 > bv) { bv = v2; bi = t + 256; }
    rv[t] = bv; ri[t] = bi;
    __syncthreads();
    for (int off = 128; off > 0; off >>= 1) {
      if (t < off && rv[t + off] > rv[t]) { rv[t] = rv[t + off]; ri[t] = ri[t + off]; }
      __syncthreads();
    }
    if (t == 0) { ridx[p * 4 + sel] = ri[0]; lg[ri[0]] = -INFINITY; }
    __syncthreads();
  }
}

// ---- MFMA attention v5: zero-LDS shuffle-PV + dense head-major layouts ----
// grid (1024) = (p, half); 4 waves; wave = head = half*4+wave, all 64 q rows.
__global__ __launch_bounds__(256, 4) void k_attn(
    const float* __restrict__ q, const short* __restrict__ kbh,
    const short* __restrict__ vt, const int* __restrict__ ridx,
    float* __restrict__ ao) {
  const int bid = blockIdx.x, t = threadIdx.x;
  const int p = bid >> 1, half = bid & 1;
  const int wave = t >> 6, lane = t & 63;
  const int l15 = lane & 15, lg = lane >> 4;
  const int h = half * 4 + wave;

  const int4 ws4 = *(const int4*)(ridx + p * 4);
  const int wsa[4] = {ws4.x, ws4.y, ws4.z, ws4.w};

  const int src0 = ((lg & 1) << 5) | l15;  // lane holding lg'=(lg&1)*2
  const int src1 = src0 + 16;              // lane holding lg'=(lg&1)*2+1

  // Q B-frags hoisted (f32 + cvt, pre-scaled)
  short8 qf[4];
#pragma unroll
  for (int nt = 0; nt < 4; ++nt) {
    if (lg < 2)
      qf[nt] = cvt8s(q + ((size_t)(p * 64 + nt * 16 + l15)) * 128 + h * 16 + lg * 8, kScale);
    else
      qf[nt] = short8{0, 0, 0, 0, 0, 0, 0, 0};
  }

  float m_r[4] = {-1e30f, -1e30f, -1e30f, -1e30f};
  float l_r[4] = {0.f, 0.f, 0.f, 0.f};
  f32x4 oacc[4];
#pragma unroll
  for (int i = 0; i < 4; ++i) oacc[i] = f32x4{0.f, 0.f, 0.f, 0.f};

#pragma unroll
  for (int c = 0; c < 4; ++c) {
    const int wsel = wsa[c];
    // K A-frags from kbh: dense rows of 16 dims (32 B)
    const short* kw = kbh + ((size_t)(wsel * 8 + h)) * 1024;  // 64*16
    short8 af[4];
#pragma unroll
    for (int mt = 0; mt < 4; ++mt) {
      if (lg < 2)
        af[mt] = *(const short8*)(kw + (mt * 16 + l15) * 16 + lg * 8);
      else
        af[mt] = short8{0, 0, 0, 0, 0, 0, 0, 0};
    }
    // V^T A-frags (row=dim=l15, k=key) — contiguous per head in vt
    const short* vw = vt + (size_t)wsel * 8192 + (size_t)(h * 16 + l15) * 64 + lg * 8;
    short8 av0 = *(const short8*)(vw);
    short8 av1 = *(const short8*)(vw + 32);

#pragma unroll
    for (int nt = 0; nt < 4; ++nt) {
      // S^T = K·Q^T: col=l15=q, row=lg*4+j=key mt*16+lg*4+j
      f32x4 s[4];
#pragma unroll
      for (int mt = 0; mt < 4; ++mt)
        s[mt] = __builtin_amdgcn_mfma_f32_16x16x32_bf16(
            af[mt], qf[nt], f32x4{0.f, 0.f, 0.f, 0.f}, 0, 0, 0);
      // online softmax (per-lane q = l15)
      float mx = -1e30f;
#pragma unroll
      for (int mt = 0; mt < 4; ++mt)
#pragma unroll
        for (int j = 0; j < 4; ++j) mx = fmaxf(mx, s[mt][j]);
      mx = fmaxf(mx, __shfl_xor(mx, 16));
      mx = fmaxf(mx, __shfl_xor(mx, 32));
      float mnew = fmaxf(m_r[nt], mx);
      float sc = __expf(m_r[nt] - mnew);
      m_r[nt] = mnew;
      float ls = 0.f;
#pragma unroll
      for (int mt = 0; mt < 4; ++mt)
#pragma unroll
        for (int j = 0; j < 4; ++j) {
          float e = __expf(s[mt][j] - mnew);
          s[mt][j] = e;
          ls += e;
        }
      ls += __shfl_xor(ls, 16);
      ls += __shfl_xor(ls, 32);
      l_r[nt] = l_r[nt] * sc + ls;
      oacc[nt][0] *= sc; oacc[nt][1] *= sc;
      oacc[nt][2] *= sc; oacc[nt][3] *= sc;
      // pack P bf16 pairs: P2[mt][w] = keys mt*16+lg*4+{2w,2w+1}, q=l15
      unsigned P2[4][2];
#pragma unroll
      for (int mt = 0; mt < 4; ++mt) {
        P2[mt][0] = bfpack(s[mt][0], s[mt][1]);
        P2[mt][1] = bfpack(s[mt][2], s[mt][3]);
      }
      // P^T B-frags via shfl (verified in R8): dest lane keys lg*8..+7
#pragma unroll
      for (int kt = 0; kt < 2; ++kt) {
        unsigned lo0 = (unsigned)__shfl((int)P2[2 * kt + 0][0], src0);
        unsigned hi0 = (unsigned)__shfl((int)P2[2 * kt + 1][0], src0);
        unsigned lo1 = (unsigned)__shfl((int)P2[2 * kt + 0][1], src0);
        unsigned hi1 = (unsigned)__shfl((int)P2[2 * kt + 1][1], src0);
        unsigned lo2 = (unsigned)__shfl((int)P2[2 * kt + 0][0], src1);
        unsigned hi2 = (unsigned)__shfl((int)P2[2 * kt + 1][0], src1);
        unsigned lo3 = (unsigned)__shfl((int)P2[2 * kt + 0][1], src1);
        unsigned hi3 = (unsigned)__shfl((int)P2[2 * kt + 1][1], src1);
        u32x4 bw;
        bw[0] = (lg < 2) ? lo0 : hi0;
        bw[1] = (lg < 2) ? lo1 : hi1;
        bw[2] = (lg < 2) ? lo2 : hi2;
        bw[3] = (lg < 2) ? lo3 : hi3;
        short8 bfr = __builtin_bit_cast(short8, bw);
        oacc[nt] = __builtin_amdgcn_mfma_f32_16x16x32_bf16(
            kt == 0 ? av0 : av1, bfr, oacc[nt], 0, 0, 0);
      }
    }
  }

  // epilogue: lane owns q=l15; dims lg*4+j contiguous float4
#pragma unroll
  for (int nt = 0; nt < 4; ++nt) {
    float inv = 1.f / l_r[nt];
    float4 st;
    st.x = oacc[nt][0] * inv; st.y = oacc[nt][1] * inv;
    st.z = oacc[nt][2] * inv; st.w = oacc[nt][3] * inv;
    int qpix = nt * 16 + l15;
    *(float4*)(ao + (size_t)voxel_row(p, qpix) * 128 + h * 16 + lg * 4) = st;
  }
}

// ---- output projection, MFMA, in-place (unchanged) ----
__global__ __launch_bounds__(256) void k_proj(
    float* io, const short* __restrict__ wpk, const float* __restrict__ bias) {
  __shared__ short sX[64][136];
  const int p = blockIdx.x, t = threadIdx.x;
  const int wave = t >> 6, lane = t & 63, l15 = lane & 15, lg = lane >> 4;
#pragma unroll
  for (int r = 0; r < 4; ++r) {
    int unit = t + r * 256;
    int row = unit >> 4, u = unit & 15;
    *(short8*)(&sX[row][u * 8]) =
        cvt8(io + (size_t)voxel_row(p, row) * 128 + u * 8);
  }
  __syncthreads();
  f32x4 acc[4][2];
#pragma unroll
  for (int mt = 0; mt < 4; ++mt) {
    acc[mt][0] = f32x4{0.f, 0.f, 0.f, 0.f};
    acc[mt][1] = f32x4{0.f, 0.f, 0.f, 0.f};
  }
#pragma unroll
  for (int ks = 0; ks < 4; ++ks) {
    short8 a[4];
#pragma unroll
    for (int mt = 0; mt < 4; ++mt)
      a[mt] = *(const short8*)(&sX[mt * 16 + l15][ks * 32 + lg * 8]);
#pragma unroll
    for (int nt = 0; nt < 2; ++nt) {
      int ntg = wave * 2 + nt;
      short8 b = *(const short8*)(wpk + ((size_t)(ntg * 4 + ks) * 64 + lane) * 8);
#pragma unroll
      for (int mt = 0; mt < 4; ++mt)
        acc[mt][nt] = __builtin_amdgcn_mfma_f32_16x16x32_bf16(a[mt], b, acc[mt][nt], 0, 0, 0);
    }
  }
#pragma unroll
  for (int nt = 0; nt < 2; ++nt) {
    int n = (wave * 2 + nt) * 16 + l15;
    float bv = bias[n];
#pragma unroll
    for (int mt = 0; mt < 4; ++mt)
#pragma unroll
      for (int j = 0; j < 4; ++j)
        io[(size_t)voxel_row(p, mt * 16 + lg * 4 + j) * 128 + n] = acc[mt][nt][j] + bv;
  }
}

}  // namespace

extern "C" void kernel_launch(void* const* d_in, const int* in_sizes, int n_in,
                              void* d_out, int out_size, void* d_ws, size_t ws_size,
                              hipStream_t stream) {
  (void)in_sizes; (void)n_in; (void)out_size; (void)ws_size;
  const float* x = (const float*)d_in[0];
  const float* w_qkv = (const float*)d_in[1];
  const float* b_qkv = (const float*)d_in[2];
  const float* w_o = (const float*)d_in[3];
  const float* b_o = (const float*)d_in[4];

  float* out = (float*)d_out;
  float* q = out + 4194304;
  float* k = q + 4194304;
  float* v = k + 4194304;

  float* qwin = (float*)d_ws;                 // 512*128 f32
  float* kwin = qwin + 65536;                 // 512*128 f32
  int* ridx = (int*)(kwin + 65536);           // 512*4 i32
  short* wpk_qkv = (short*)(ridx + 2048);     // 96 KB
  short* wpk_o = wpk_qkv + 49152;             // 32 KB
  short* vt = wpk_o + 16384;                  // 512*128*64 bf16 = 8 MB
  short* kbh = vt + 4194304;                  // 512*8*64*16 bf16 = 8 MB

  k_pack<<<96, 64, 0, stream>>>(w_qkv, wpk_qkv, 384);
  k_pack<<<32, 64, 0, stream>>>(w_o, wpk_o, 128);
  k_qkv<<<512, 256, 0, stream>>>(x, wpk_qkv, b_qkv, w_qkv, q, k, v, vt, kbh, qwin, kwin);
  k_route<<<512, 256, 0, stream>>>(qwin, kwin, ridx);
  k_attn<<<1024, 256, 0, stream>>>(q, kbh, vt, ridx, out);
  k_proj<<<512, 256, 0, stream>>>(out, wpk_o, b_o);
}

// Round 11
// 87.627 us; speedup vs baseline: 1.3531x; 1.0067x over previous
//
#include <hip/hip_runtime.h>
#include <cmath>

namespace {

typedef __attribute__((ext_vector_type(8))) short short8;
typedef __attribute__((ext_vector_type(4))) float f32x4;
typedef __attribute__((ext_vector_type(4))) unsigned u32x4;

constexpr float kScale = 0.08838834764831845f;  // 128^-0.5

__device__ __forceinline__ int voxel_row(int p, int pix) {
  int pd = p >> 6, ph = (p >> 3) & 7, pw = p & 7;
  int iz = pix >> 4, iy = (pix >> 2) & 3, ix = pix & 3;
  return (((pd * 4 + iz) * 32 + (ph * 4 + iy)) * 32 + (pw * 4 + ix));
}

__device__ __forceinline__ float dot4(float4 a, float4 b) {
  return a.x * b.x + a.y * b.y + a.z * b.z + a.w * b.w;
}

__device__ __forceinline__ short bf16c(float f) {
  unsigned u = __builtin_bit_cast(unsigned, f);
  u += 0x7fffu + ((u >> 16) & 1u);
  return (short)(u >> 16);
}

__device__ __forceinline__ unsigned bfpack(float lo, float hi) {
  return (unsigned)(unsigned short)bf16c(lo) |
         ((unsigned)(unsigned short)bf16c(hi) << 16);
}

__device__ __forceinline__ short8 cvt8(const float* src) {
  float4 a = *(const float4*)src, b = *(const float4*)(src + 4);
  short8 o;
  o[0] = bf16c(a.x); o[1] = bf16c(a.y); o[2] = bf16c(a.z); o[3] = bf16c(a.w);
  o[4] = bf16c(b.x); o[5] = bf16c(b.y); o[6] = bf16c(b.z); o[7] = bf16c(b.w);
  return o;
}

// ---- pack weights into per-lane MFMA B-fragments (both matrices, 1 launch) --
__global__ __launch_bounds__(64) void k_pack2(
    const float* __restrict__ wqkv, const float* __restrict__ wo,
    short* __restrict__ dstq, short* __restrict__ dsto) {
  const int lane = threadIdx.x;
  const float* w;
  short* dst;
  int fid, N;
  if (blockIdx.x < 96) {
    w = wqkv; dst = dstq; fid = blockIdx.x; N = 384;
  } else {
    w = wo; dst = dsto; fid = blockIdx.x - 96; N = 128;
  }
  const int ntile = fid >> 2, ks = fid & 3;
  const int k0 = ks * 32 + (lane >> 4) * 8, col = ntile * 16 + (lane & 15);
  short8 o;
#pragma unroll
  for (int i = 0; i < 8; ++i) o[i] = bf16c(w[(size_t)(k0 + i) * N + col]);
  *(short8*)(dst + ((size_t)fid * 64 + lane) * 8) = o;
}

// ---- QKV projection, MFMA; emits q/k/v f32 (outputs), vt (V^T bf16),
// kbh/qbh (K,Q bf16 head-major; qbh pre-scaled), + exact-f32 window means ----
__global__ __launch_bounds__(256) void k_qkv(
    const float* __restrict__ x, const short* __restrict__ wpk,
    const float* __restrict__ bias, const float* __restrict__ wfull,
    float* __restrict__ q, float* __restrict__ k, float* __restrict__ v,
    short* __restrict__ vt, short* __restrict__ kbh, short* __restrict__ qbh,
    float* __restrict__ qwin, float* __restrict__ kwin) {
  __shared__ short sX[64][136];
  __shared__ float xpart[16][16][8];
  __shared__ float xm[128];
  const int p = blockIdx.x, t = threadIdx.x;
  const int wave = t >> 6, lane = t & 63, l15 = lane & 15, lg = lane >> 4;

  float ps[8] = {0.f, 0.f, 0.f, 0.f, 0.f, 0.f, 0.f, 0.f};
#pragma unroll
  for (int r = 0; r < 4; ++r) {
    int unit = t + r * 256;
    int row = unit >> 4, u = unit & 15;
    const float* src = x + (size_t)voxel_row(p, row) * 128 + u * 8;
    float4 a = *(const float4*)src, b = *(const float4*)(src + 4);
    ps[0] += a.x; ps[1] += a.y; ps[2] += a.z; ps[3] += a.w;
    ps[4] += b.x; ps[5] += b.y; ps[6] += b.z; ps[7] += b.w;
    short8 o;
    o[0] = bf16c(a.x); o[1] = bf16c(a.y); o[2] = bf16c(a.z); o[3] = bf16c(a.w);
    o[4] = bf16c(b.x); o[5] = bf16c(b.y); o[6] = bf16c(b.z); o[7] = bf16c(b.w);
    *(short8*)(&sX[row][u * 8]) = o;
  }
#pragma unroll
  for (int i = 0; i < 8; ++i) xpart[t >> 4][t & 15][i] = ps[i];
  __syncthreads();
  if (t < 128) {
    float s = 0.f;
#pragma unroll
    for (int g = 0; g < 16; ++g) s += xpart[g][t >> 3][t & 7];
    xm[t] = s * (1.f / 64.f);
  }
  __syncthreads();

  f32x4 acc[4][6];
#pragma unroll
  for (int mt = 0; mt < 4; ++mt)
#pragma unroll
    for (int nt = 0; nt < 6; ++nt) acc[mt][nt] = f32x4{0.f, 0.f, 0.f, 0.f};
#pragma unroll
  for (int ks = 0; ks < 4; ++ks) {
    short8 a[4];
#pragma unroll
    for (int mt = 0; mt < 4; ++mt)
      a[mt] = *(const short8*)(&sX[mt * 16 + l15][ks * 32 + lg * 8]);
#pragma unroll
    for (int nt = 0; nt < 6; ++nt) {
      int ntg = wave * 6 + nt;
      short8 b = *(const short8*)(wpk + ((size_t)(ntg * 4 + ks) * 64 + lane) * 8);
#pragma unroll
      for (int mt = 0; mt < 4; ++mt)
        acc[mt][nt] = __builtin_amdgcn_mfma_f32_16x16x32_bf16(a[mt], b, acc[mt][nt], 0, 0, 0);
    }
  }
#pragma unroll
  for (int nt = 0; nt < 6; ++nt) {
    int n = (wave * 6 + nt) * 16 + l15;
    float bv = bias[n];
    float* dst = n < 128 ? q : (n < 256 ? k : v);
    int col = n & 127;
#pragma unroll
    for (int mt = 0; mt < 4; ++mt) {
      float o0 = acc[mt][nt][0] + bv, o1 = acc[mt][nt][1] + bv;
      float o2 = acc[mt][nt][2] + bv, o3 = acc[mt][nt][3] + bv;
      int row0 = mt * 16 + lg * 4;
      dst[(size_t)(p * 64 + row0 + 0) * 128 + col] = o0;
      dst[(size_t)(p * 64 + row0 + 1) * 128 + col] = o1;
      dst[(size_t)(p * 64 + row0 + 2) * 128 + col] = o2;
      dst[(size_t)(p * 64 + row0 + 3) * 128 + col] = o3;
      if (n >= 256) {  // V^T bf16: vt[p][dim][key]
        uint2 pk;
        pk.x = bfpack(o0, o1);
        pk.y = bfpack(o2, o3);
        *(uint2*)(vt + (size_t)p * 8192 + (size_t)(n - 256) * 64 + row0) = pk;
      } else if (n >= 128) {  // K bf16 head-major: kbh[p][h][key][16]
        int hh = (n - 128) >> 4, d = (n - 128) & 15;
        short* kd = kbh + (((size_t)(p * 8 + hh)) * 64 + row0) * 16 + d;
        kd[0] = bf16c(o0);
        kd[16] = bf16c(o1);
        kd[32] = bf16c(o2);
        kd[48] = bf16c(o3);
      } else {  // Q bf16 head-major, pre-scaled: qbh[p][h][q][16]
        int hh = n >> 4, d = n & 15;
        short* qd = qbh + (((size_t)(p * 8 + hh)) * 64 + row0) * 16 + d;
        qd[0] = bf16c(o0 * kScale);
        qd[16] = bf16c(o1 * kScale);
        qd[32] = bf16c(o2 * kScale);
        qd[48] = bf16c(o3 * kScale);
      }
    }
  }

  // fused window-mean projection (exact f32): win = mean(x) @ W_qk + b
  {
    float acc2 = bias[t];
    for (int kk = 0; kk < 128; ++kk)
      acc2 = fmaf(xm[kk], wfull[(size_t)kk * 384 + t], acc2);
    if (t < 128) qwin[p * 128 + t] = acc2;
    else kwin[p * 128 + (t - 128)] = acc2;
  }
}

// ---------------- routing (unchanged) ----------------
__global__ __launch_bounds__(256) void k_route(
    const float* __restrict__ qwin, const float* __restrict__ kwin,
    int* __restrict__ ridx) {
  __shared__ float qs[128];
  __shared__ float lg[512];
  __shared__ float rv[256];
  __shared__ int ri[256];
  const int p = blockIdx.x, t = threadIdx.x;
  if (t < 32) *(float4*)(&qs[t * 4]) = *(const float4*)(qwin + p * 128 + t * 4);
  __syncthreads();
  for (int jj = t; jj < 512; jj += 256) {
    const float* kr = kwin + (size_t)jj * 128;
    float s = 0.f;
    for (int c = 0; c < 128; c += 4) {
      float4 k4 = *(const float4*)(kr + c);
      float4 q4 = *(const float4*)(qs + c);
      s += dot4(q4, k4);
    }
    lg[jj] = s;
  }
  __syncthreads();
  for (int sel = 0; sel < 4; ++sel) {
    float bv = lg[t];
    int bi = t;
    float v2 = lg[t + 256];
    if (v2 > bv) { bv = v2; bi = t + 256; }
    rv[t] = bv; ri[t] = bi;
    __syncthreads();
    for (int off = 128; off > 0; off >>= 1) {
      if (t < off && rv[t + off] > rv[t]) { rv[t] = rv[t + off]; ri[t] = ri[t + off]; }
      __syncthreads();
    }
    if (t == 0) { ridx[p * 4 + sel] = ri[0]; lg[ri[0]] = -INFINITY; }
    __syncthreads();
  }
}

// ---- MFMA attention v6: zero-LDS, all-bf16 operands, block = window ----
// 512 threads, 8 independent waves (wave = head). Writes aob bf16 [p*64+q][128].
__global__ __launch_bounds__(512, 4) void k_attn(
    const short* __restrict__ qbh, const short* __restrict__ kbh,
    const short* __restrict__ vt, const int* __restrict__ ridx,
    short* __restrict__ aob) {
  const int p = blockIdx.x, t = threadIdx.x;
  const int h = t >> 6, lane = t & 63;
  const int l15 = lane & 15, lg = lane >> 4;

  const int4 ws4 = *(const int4*)(ridx + p * 4);
  const int wsa[4] = {ws4.x, ws4.y, ws4.z, ws4.w};

  const int src0 = ((lg & 1) << 5) | l15;  // lane holding lg'=(lg&1)*2
  const int src1 = src0 + 16;              // lane holding lg'=(lg&1)*2+1

  // Q B-frags: dense bf16, pre-scaled
  const short* qw = qbh + ((size_t)(p * 8 + h)) * 1024;
  short8 qf[4];
#pragma unroll
  for (int nt = 0; nt < 4; ++nt) {
    if (lg < 2)
      qf[nt] = *(const short8*)(qw + (nt * 16 + l15) * 16 + lg * 8);
    else
      qf[nt] = short8{0, 0, 0, 0, 0, 0, 0, 0};
  }

  float m_r[4] = {-1e30f, -1e30f, -1e30f, -1e30f};
  float l_r[4] = {0.f, 0.f, 0.f, 0.f};
  f32x4 oacc[4];
#pragma unroll
  for (int i = 0; i < 4; ++i) oacc[i] = f32x4{0.f, 0.f, 0.f, 0.f};

#pragma unroll
  for (int c = 0; c < 4; ++c) {
    const int wsel = wsa[c];
    const short* kw = kbh + ((size_t)(wsel * 8 + h)) * 1024;
    short8 af[4];
#pragma unroll
    for (int mt = 0; mt < 4; ++mt) {
      if (lg < 2)
        af[mt] = *(const short8*)(kw + (mt * 16 + l15) * 16 + lg * 8);
      else
        af[mt] = short8{0, 0, 0, 0, 0, 0, 0, 0};
    }
    const short* vw = vt + (size_t)wsel * 8192 + (size_t)(h * 16 + l15) * 64 + lg * 8;
    short8 av0 = *(const short8*)(vw);
    short8 av1 = *(const short8*)(vw + 32);

#pragma unroll
    for (int nt = 0; nt < 4; ++nt) {
      // S^T = K·Q^T: col=l15=q, row=lg*4+j=key mt*16+lg*4+j
      f32x4 s[4];
#pragma unroll
      for (int mt = 0; mt < 4; ++mt)
        s[mt] = __builtin_amdgcn_mfma_f32_16x16x32_bf16(
            af[mt], qf[nt], f32x4{0.f, 0.f, 0.f, 0.f}, 0, 0, 0);
      // online softmax (per-lane q = l15)
      float mx = -1e30f;
#pragma unroll
      for (int mt = 0; mt < 4; ++mt)
#pragma unroll
        for (int j = 0; j < 4; ++j) mx = fmaxf(mx, s[mt][j]);
      mx = fmaxf(mx, __shfl_xor(mx, 16));
      mx = fmaxf(mx, __shfl_xor(mx, 32));
      float mnew = fmaxf(m_r[nt], mx);
      float sc = __expf(m_r[nt] - mnew);
      m_r[nt] = mnew;
      float ls = 0.f;
#pragma unroll
      for (int mt = 0; mt < 4; ++mt)
#pragma unroll
        for (int j = 0; j < 4; ++j) {
          float e = __expf(s[mt][j] - mnew);
          s[mt][j] = e;
          ls += e;
        }
      ls += __shfl_xor(ls, 16);
      ls += __shfl_xor(ls, 32);
      l_r[nt] = l_r[nt] * sc + ls;
      oacc[nt][0] *= sc; oacc[nt][1] *= sc;
      oacc[nt][2] *= sc; oacc[nt][3] *= sc;
      // pack P bf16 pairs: P2[mt][w] = keys mt*16+lg*4+{2w,2w+1}, q=l15
      unsigned P2[4][2];
#pragma unroll
      for (int mt = 0; mt < 4; ++mt) {
        P2[mt][0] = bfpack(s[mt][0], s[mt][1]);
        P2[mt][1] = bfpack(s[mt][2], s[mt][3]);
      }
      // P^T B-frags via shfl: dest lane keys lg*8..+7
#pragma unroll
      for (int kt = 0; kt < 2; ++kt) {
        unsigned lo0 = (unsigned)__shfl((int)P2[2 * kt + 0][0], src0);
        unsigned hi0 = (unsigned)__shfl((int)P2[2 * kt + 1][0], src0);
        unsigned lo1 = (unsigned)__shfl((int)P2[2 * kt + 0][1], src0);
        unsigned hi1 = (unsigned)__shfl((int)P2[2 * kt + 1][1], src0);
        unsigned lo2 = (unsigned)__shfl((int)P2[2 * kt + 0][0], src1);
        unsigned hi2 = (unsigned)__shfl((int)P2[2 * kt + 1][0], src1);
        unsigned lo3 = (unsigned)__shfl((int)P2[2 * kt + 0][1], src1);
        unsigned hi3 = (unsigned)__shfl((int)P2[2 * kt + 1][1], src1);
        u32x4 bw;
        bw[0] = (lg < 2) ? lo0 : hi0;
        bw[1] = (lg < 2) ? lo1 : hi1;
        bw[2] = (lg < 2) ? lo2 : hi2;
        bw[3] = (lg < 2) ? lo3 : hi3;
        short8 bfr = __builtin_bit_cast(short8, bw);
        oacc[nt] = __builtin_amdgcn_mfma_f32_16x16x32_bf16(
            kt == 0 ? av0 : av1, bfr, oacc[nt], 0, 0, 0);
      }
    }
  }

  // epilogue: lane owns q=l15, dims h*16+lg*4..+3 -> bf16 uint2 store
#pragma unroll
  for (int nt = 0; nt < 4; ++nt) {
    float inv = 1.f / l_r[nt];
    uint2 pk;
    pk.x = bfpack(oacc[nt][0] * inv, oacc[nt][1] * inv);
    pk.y = bfpack(oacc[nt][2] * inv, oacc[nt][3] * inv);
    int qpix = nt * 16 + l15;
    *(uint2*)(aob + ((size_t)(p * 64 + qpix)) * 128 + h * 16 + lg * 4) = pk;
  }
}

// ---- output projection from aob (bf16, dense): zero LDS, direct A-frags ----
__global__ __launch_bounds__(256) void k_proj(
    const short* __restrict__ aob, const short* __restrict__ wpk,
    const float* __restrict__ bias, float* __restrict__ out) {
  const int p = blockIdx.x, t = threadIdx.x;
  const int wave = t >> 6, lane = t & 63, l15 = lane & 15, lg = lane >> 4;
  f32x4 acc[4][2];
#pragma unroll
  for (int mt = 0; mt < 4; ++mt) {
    acc[mt][0] = f32x4{0.f, 0.f, 0.f, 0.f};
    acc[mt][1] = f32x4{0.f, 0.f, 0.f, 0.f};
  }
#pragma unroll
  for (int ks = 0; ks < 4; ++ks) {
    short8 a[4];
#pragma unroll
    for (int mt = 0; mt < 4; ++mt)
      a[mt] = *(const short8*)(aob + ((size_t)(p * 64 + mt * 16 + l15)) * 128 + ks * 32 + lg * 8);
#pragma unroll
    for (int nt = 0; nt < 2; ++nt) {
      int ntg = wave * 2 + nt;
      short8 b = *(const short8*)(wpk + ((size_t)(ntg * 4 + ks) * 64 + lane) * 8);
#pragma unroll
      for (int mt = 0; mt < 4; ++mt)
        acc[mt][nt] = __builtin_amdgcn_mfma_f32_16x16x32_bf16(a[mt], b, acc[mt][nt], 0, 0, 0);
    }
  }
#pragma unroll
  for (int nt = 0; nt < 2; ++nt) {
    int n = (wave * 2 + nt) * 16 + l15;
    float bv = bias[n];
#pragma unroll
    for (int mt = 0; mt < 4; ++mt)
#pragma unroll
      for (int j = 0; j < 4; ++j)
        out[(size_t)voxel_row(p, mt * 16 + lg * 4 + j) * 128 + n] = acc[mt][nt][j] + bv;
  }
}

}  // namespace

extern "C" void kernel_launch(void* const* d_in, const int* in_sizes, int n_in,
                              void* d_out, int out_size, void* d_ws, size_t ws_size,
                              hipStream_t stream) {
  (void)in_sizes; (void)n_in; (void)out_size; (void)ws_size;
  const float* x = (const float*)d_in[0];
  const float* w_qkv = (const float*)d_in[1];
  const float* b_qkv = (const float*)d_in[2];
  const float* w_o = (const float*)d_in[3];
  const float* b_o = (const float*)d_in[4];

  float* out = (float*)d_out;
  float* q = out + 4194304;
  float* k = q + 4194304;
  float* v = k + 4194304;

  float* qwin = (float*)d_ws;                 // 512*128 f32
  float* kwin = qwin + 65536;                 // 512*128 f32
  int* ridx = (int*)(kwin + 65536);           // 512*4 i32
  short* wpk_qkv = (short*)(ridx + 2048);     // 96 KB
  short* wpk_o = wpk_qkv + 49152;             // 32 KB
  short* vt = wpk_o + 16384;                  // 8 MB
  short* kbh = vt + 4194304;                  // 8 MB
  short* qbh = kbh + 4194304;                 // 8 MB
  short* aob = qbh + 4194304;                 // 8 MB

  k_pack2<<<128, 64, 0, stream>>>(w_qkv, w_o, wpk_qkv, wpk_o);
  k_qkv<<<512, 256, 0, stream>>>(x, wpk_qkv, b_qkv, w_qkv, q, k, v, vt, kbh, qbh, qwin, kwin);
  k_route<<<512, 256, 0, stream>>>(qwin, kwin, ridx);
  k_attn<<<512, 512, 0, stream>>>(qbh, kbh, vt, ridx, aob);
  k_proj<<<512, 256, 0, stream>>>(aob, wpk_o, b_o, out);
}

// Round 12
// 78.445 us; speedup vs baseline: 1.5115x; 1.1171x over previous
//
#include <hip/hip_runtime.h>
#include <cmath>

namespace {

typedef __attribute__((ext_vector_type(8))) short short8;
typedef __attribute__((ext_vector_type(4))) float f32x4;
typedef __attribute__((ext_vector_type(4))) unsigned u32x4;

constexpr float kScale = 0.08838834764831845f;  // 128^-0.5

__device__ __forceinline__ int voxel_row(int p, int pix) {
  int pd = p >> 6, ph = (p >> 3) & 7, pw = p & 7;
  int iz = pix >> 4, iy = (pix >> 2) & 3, ix = pix & 3;
  return (((pd * 4 + iz) * 32 + (ph * 4 + iy)) * 32 + (pw * 4 + ix));
}

__device__ __forceinline__ float dot4(float4 a, float4 b) {
  return a.x * b.x + a.y * b.y + a.z * b.z + a.w * b.w;
}

__device__ __forceinline__ short bf16c(float f) {
  unsigned u = __builtin_bit_cast(unsigned, f);
  u += 0x7fffu + ((u >> 16) & 1u);
  return (short)(u >> 16);
}

__device__ __forceinline__ unsigned bfpack(float lo, float hi) {
  return (unsigned)(unsigned short)bf16c(lo) |
         ((unsigned)(unsigned short)bf16c(hi) << 16);
}

// ---- pack weights into per-lane MFMA B-fragments ----
__global__ __launch_bounds__(64) void k_pack2(
    const float* __restrict__ wqkv, const float* __restrict__ wo,
    short* __restrict__ dstq, short* __restrict__ dsto) {
  const int lane = threadIdx.x;
  const float* w;
  short* dst;
  int fid, N;
  if (blockIdx.x < 96) {
    w = wqkv; dst = dstq; fid = blockIdx.x; N = 384;
  } else {
    w = wo; dst = dsto; fid = blockIdx.x - 96; N = 128;
  }
  const int ntile = fid >> 2, ks = fid & 3;
  const int k0 = ks * 32 + (lane >> 4) * 8, col = ntile * 16 + (lane & 15);
  short8 o;
#pragma unroll
  for (int i = 0; i < 8; ++i) o[i] = bf16c(w[(size_t)(k0 + i) * N + col]);
  *(short8*)(dst + ((size_t)fid * 64 + lane) * 8) = o;
}

// ---- QKV projection: 512 thr / 8 waves x 3 col-tiles; emits q/k/v f32,
// vt / kbh / qbh bf16, + exact-f32 window means ----
__global__ __launch_bounds__(512, 4) void k_qkv(
    const float* __restrict__ x, const short* __restrict__ wpk,
    const float* __restrict__ bias, const float* __restrict__ wfull,
    float* __restrict__ q, float* __restrict__ k, float* __restrict__ v,
    short* __restrict__ vt, short* __restrict__ kbh, short* __restrict__ qbh,
    float* __restrict__ qwin, float* __restrict__ kwin) {
  __shared__ short sX[64][136];
  __shared__ float xpart[8][16][8];
  __shared__ float xm[128];
  const int p = blockIdx.x, t = threadIdx.x;
  const int wave = t >> 6, lane = t & 63, l15 = lane & 15, lg = lane >> 4;

  float ps[8] = {0.f, 0.f, 0.f, 0.f, 0.f, 0.f, 0.f, 0.f};
#pragma unroll
  for (int r = 0; r < 2; ++r) {
    int unit = t + r * 512;
    int row = unit >> 4, u = unit & 15;  // u == l15
    const float* src = x + (size_t)voxel_row(p, row) * 128 + u * 8;
    float4 a = *(const float4*)src, b = *(const float4*)(src + 4);
    ps[0] += a.x; ps[1] += a.y; ps[2] += a.z; ps[3] += a.w;
    ps[4] += b.x; ps[5] += b.y; ps[6] += b.z; ps[7] += b.w;
    short8 o;
    o[0] = bf16c(a.x); o[1] = bf16c(a.y); o[2] = bf16c(a.z); o[3] = bf16c(a.w);
    o[4] = bf16c(b.x); o[5] = bf16c(b.y); o[6] = bf16c(b.z); o[7] = bf16c(b.w);
    *(short8*)(&sX[row][u * 8]) = o;
  }
  // wave-level reduce over the 8 rows this wave staged
#pragma unroll
  for (int i = 0; i < 8; ++i) {
    ps[i] += __shfl_xor(ps[i], 16);
    ps[i] += __shfl_xor(ps[i], 32);
  }
  if (lg == 0)
#pragma unroll
    for (int i = 0; i < 8; ++i) xpart[wave][l15][i] = ps[i];
  __syncthreads();  // sX + xpart complete
  if (t < 128) {
    float s = 0.f;
#pragma unroll
    for (int w8 = 0; w8 < 8; ++w8) s += xpart[w8][t >> 3][t & 7];
    xm[t] = s * (1.f / 64.f);
  }

  f32x4 acc[4][3];
#pragma unroll
  for (int mt = 0; mt < 4; ++mt)
#pragma unroll
    for (int nt = 0; nt < 3; ++nt) acc[mt][nt] = f32x4{0.f, 0.f, 0.f, 0.f};
#pragma unroll
  for (int ks = 0; ks < 4; ++ks) {
    short8 a[4];
#pragma unroll
    for (int mt = 0; mt < 4; ++mt)
      a[mt] = *(const short8*)(&sX[mt * 16 + l15][ks * 32 + lg * 8]);
#pragma unroll
    for (int nt = 0; nt < 3; ++nt) {
      int ntg = wave * 3 + nt;
      short8 b = *(const short8*)(wpk + ((size_t)(ntg * 4 + ks) * 64 + lane) * 8);
#pragma unroll
      for (int mt = 0; mt < 4; ++mt)
        acc[mt][nt] = __builtin_amdgcn_mfma_f32_16x16x32_bf16(a[mt], b, acc[mt][nt], 0, 0, 0);
    }
  }
#pragma unroll
  for (int nt = 0; nt < 3; ++nt) {
    int n = (wave * 3 + nt) * 16 + l15;
    float bv = bias[n];
    float* dst = n < 128 ? q : (n < 256 ? k : v);
    int col = n & 127;
#pragma unroll
    for (int mt = 0; mt < 4; ++mt) {
      float o0 = acc[mt][nt][0] + bv, o1 = acc[mt][nt][1] + bv;
      float o2 = acc[mt][nt][2] + bv, o3 = acc[mt][nt][3] + bv;
      int row0 = mt * 16 + lg * 4;
      dst[(size_t)(p * 64 + row0 + 0) * 128 + col] = o0;
      dst[(size_t)(p * 64 + row0 + 1) * 128 + col] = o1;
      dst[(size_t)(p * 64 + row0 + 2) * 128 + col] = o2;
      dst[(size_t)(p * 64 + row0 + 3) * 128 + col] = o3;
      if (n >= 256) {  // V^T bf16: vt[p][dim][key]
        uint2 pk;
        pk.x = bfpack(o0, o1);
        pk.y = bfpack(o2, o3);
        *(uint2*)(vt + (size_t)p * 8192 + (size_t)(n - 256) * 64 + row0) = pk;
      } else if (n >= 128) {  // K bf16 head-major: kbh[p][h][key][16]
        int hh = (n - 128) >> 4, d = (n - 128) & 15;
        short* kd = kbh + (((size_t)(p * 8 + hh)) * 64 + row0) * 16 + d;
        kd[0] = bf16c(o0);
        kd[16] = bf16c(o1);
        kd[32] = bf16c(o2);
        kd[48] = bf16c(o3);
      } else {  // Q bf16 head-major, pre-scaled: qbh[p][h][q][16]
        int hh = n >> 4, d = n & 15;
        short* qd = qbh + (((size_t)(p * 8 + hh)) * 64 + row0) * 16 + d;
        qd[0] = bf16c(o0 * kScale);
        qd[16] = bf16c(o1 * kScale);
        qd[32] = bf16c(o2 * kScale);
        qd[48] = bf16c(o3 * kScale);
      }
    }
  }

  __syncthreads();  // xm ready (and everyone past sX use)
  if (t < 256) {    // exact-f32 window-mean projection for routing
    float acc2 = bias[t];
    for (int kk = 0; kk < 128; ++kk)
      acc2 = fmaf(xm[kk], wfull[(size_t)kk * 384 + t], acc2);
    if (t < 128) qwin[p * 128 + t] = acc2;
    else kwin[p * 128 + (t - 128)] = acc2;
  }
}

// ---- FUSED routing + attention + out-projection; one block per window ----
// 512 thr, 8 waves (wave = head). Route: 512 logits + top-4 (f32, exact).
// Attn: zero-LDS shuffle-PV (verified). Proj: O via sO LDS, wave = col-tile.
__global__ __launch_bounds__(512, 4) void k_attn(
    const short* __restrict__ qbh, const short* __restrict__ kbh,
    const short* __restrict__ vt, const float* __restrict__ qwin,
    const float* __restrict__ kwin, const short* __restrict__ wpk_o,
    const float* __restrict__ b_o, float* __restrict__ out) {
  __shared__ float lgits[512];
  __shared__ float rv[256];
  __shared__ int ri[256];
  __shared__ float qs[128];
  __shared__ int widx[4];
  __shared__ short sO[64][136];

  const int p = blockIdx.x, t = threadIdx.x;
  const int h = t >> 6, lane = t & 63;
  const int l15 = lane & 15, lg = lane >> 4;

  // Q B-frags issued early (independent of routing)
  const short* qw = qbh + ((size_t)(p * 8 + h)) * 1024;
  short8 qf[4];
#pragma unroll
  for (int nt = 0; nt < 4; ++nt) {
    if (lg < 2)
      qf[nt] = *(const short8*)(qw + (nt * 16 + l15) * 16 + lg * 8);
    else
      qf[nt] = short8{0, 0, 0, 0, 0, 0, 0, 0};
  }

  // ---- routing ----
  if (t < 32) *(float4*)(&qs[t * 4]) = *(const float4*)(qwin + p * 128 + t * 4);
  __syncthreads();
  {
    const float* kr = kwin + (size_t)t * 128;
    float s = 0.f;
    for (int c = 0; c < 128; c += 4)
      s += dot4(*(const float4*)(qs + c), *(const float4*)(kr + c));
    lgits[t] = s;
  }
  __syncthreads();
  for (int sel = 0; sel < 4; ++sel) {
    if (t < 256) {
      float bv = lgits[t];
      int bi = t;
      float v2 = lgits[t + 256];
      if (v2 > bv) { bv = v2; bi = t + 256; }
      rv[t] = bv; ri[t] = bi;
    }
    __syncthreads();
    for (int off = 128; off > 0; off >>= 1) {
      if (t < off && rv[t + off] > rv[t]) { rv[t] = rv[t + off]; ri[t] = ri[t + off]; }
      __syncthreads();
    }
    if (t == 0) { widx[sel] = ri[0]; lgits[ri[0]] = -INFINITY; }
    __syncthreads();
  }

  const int src0 = ((lg & 1) << 5) | l15;
  const int src1 = src0 + 16;

  float m_r[4] = {-1e30f, -1e30f, -1e30f, -1e30f};
  float l_r[4] = {0.f, 0.f, 0.f, 0.f};
  f32x4 oacc[4];
#pragma unroll
  for (int i = 0; i < 4; ++i) oacc[i] = f32x4{0.f, 0.f, 0.f, 0.f};

  // ---- attention ----
#pragma unroll
  for (int c = 0; c < 4; ++c) {
    const int wsel = widx[c];
    const short* kw = kbh + ((size_t)(wsel * 8 + h)) * 1024;
    short8 af[4];
#pragma unroll
    for (int mt = 0; mt < 4; ++mt) {
      if (lg < 2)
        af[mt] = *(const short8*)(kw + (mt * 16 + l15) * 16 + lg * 8);
      else
        af[mt] = short8{0, 0, 0, 0, 0, 0, 0, 0};
    }
    const short* vw = vt + (size_t)wsel * 8192 + (size_t)(h * 16 + l15) * 64 + lg * 8;
    short8 av0 = *(const short8*)(vw);
    short8 av1 = *(const short8*)(vw + 32);

#pragma unroll
    for (int nt = 0; nt < 4; ++nt) {
      f32x4 s[4];
#pragma unroll
      for (int mt = 0; mt < 4; ++mt)
        s[mt] = __builtin_amdgcn_mfma_f32_16x16x32_bf16(
            af[mt], qf[nt], f32x4{0.f, 0.f, 0.f, 0.f}, 0, 0, 0);
      float mx = -1e30f;
#pragma unroll
      for (int mt = 0; mt < 4; ++mt)
#pragma unroll
        for (int j = 0; j < 4; ++j) mx = fmaxf(mx, s[mt][j]);
      mx = fmaxf(mx, __shfl_xor(mx, 16));
      mx = fmaxf(mx, __shfl_xor(mx, 32));
      float mnew = fmaxf(m_r[nt], mx);
      float sc = __expf(m_r[nt] - mnew);
      m_r[nt] = mnew;
      float ls = 0.f;
#pragma unroll
      for (int mt = 0; mt < 4; ++mt)
#pragma unroll
        for (int j = 0; j < 4; ++j) {
          float e = __expf(s[mt][j] - mnew);
          s[mt][j] = e;
          ls += e;
        }
      ls += __shfl_xor(ls, 16);
      ls += __shfl_xor(ls, 32);
      l_r[nt] = l_r[nt] * sc + ls;
      oacc[nt][0] *= sc; oacc[nt][1] *= sc;
      oacc[nt][2] *= sc; oacc[nt][3] *= sc;
      unsigned P2[4][2];
#pragma unroll
      for (int mt = 0; mt < 4; ++mt) {
        P2[mt][0] = bfpack(s[mt][0], s[mt][1]);
        P2[mt][1] = bfpack(s[mt][2], s[mt][3]);
      }
#pragma unroll
      for (int kt = 0; kt < 2; ++kt) {
        unsigned lo0 = (unsigned)__shfl((int)P2[2 * kt + 0][0], src0);
        unsigned hi0 = (unsigned)__shfl((int)P2[2 * kt + 1][0], src0);
        unsigned lo1 = (unsigned)__shfl((int)P2[2 * kt + 0][1], src0);
        unsigned hi1 = (unsigned)__shfl((int)P2[2 * kt + 1][1], src0);
        unsigned lo2 = (unsigned)__shfl((int)P2[2 * kt + 0][0], src1);
        unsigned hi2 = (unsigned)__shfl((int)P2[2 * kt + 1][0], src1);
        unsigned lo3 = (unsigned)__shfl((int)P2[2 * kt + 0][1], src1);
        unsigned hi3 = (unsigned)__shfl((int)P2[2 * kt + 1][1], src1);
        u32x4 bw;
        bw[0] = (lg < 2) ? lo0 : hi0;
        bw[1] = (lg < 2) ? lo1 : hi1;
        bw[2] = (lg < 2) ? lo2 : hi2;
        bw[3] = (lg < 2) ? lo3 : hi3;
        short8 bfr = __builtin_bit_cast(short8, bw);
        oacc[nt] = __builtin_amdgcn_mfma_f32_16x16x32_bf16(
            kt == 0 ? av0 : av1, bfr, oacc[nt], 0, 0, 0);
      }
    }
  }

  // ---- O -> LDS (bf16), then per-wave out-projection col tile ----
#pragma unroll
  for (int nt = 0; nt < 4; ++nt) {
    float inv = 1.f / l_r[nt];
    uint2 pk;
    pk.x = bfpack(oacc[nt][0] * inv, oacc[nt][1] * inv);
    pk.y = bfpack(oacc[nt][2] * inv, oacc[nt][3] * inv);
    *(uint2*)(&sO[nt * 16 + l15][h * 16 + lg * 4]) = pk;
  }
  __syncthreads();

  f32x4 pacc[4];
#pragma unroll
  for (int mt = 0; mt < 4; ++mt) pacc[mt] = f32x4{0.f, 0.f, 0.f, 0.f};
#pragma unroll
  for (int ks = 0; ks < 4; ++ks) {
    short8 a[4];
#pragma unroll
    for (int mt = 0; mt < 4; ++mt)
      a[mt] = *(const short8*)(&sO[mt * 16 + l15][ks * 32 + lg * 8]);
    short8 b = *(const short8*)(wpk_o + ((size_t)(h * 4 + ks) * 64 + lane) * 8);
#pragma unroll
    for (int mt = 0; mt < 4; ++mt)
      pacc[mt] = __builtin_amdgcn_mfma_f32_16x16x32_bf16(a[mt], b, pacc[mt], 0, 0, 0);
  }
  {
    int n = h * 16 + l15;
    float bv = b_o[n];
#pragma unroll
    for (int mt = 0; mt < 4; ++mt)
#pragma unroll
      for (int j = 0; j < 4; ++j)
        out[(size_t)voxel_row(p, mt * 16 + lg * 4 + j) * 128 + n] = pacc[mt][j] + bv;
  }
}

}  // namespace

extern "C" void kernel_launch(void* const* d_in, const int* in_sizes, int n_in,
                              void* d_out, int out_size, void* d_ws, size_t ws_size,
                              hipStream_t stream) {
  (void)in_sizes; (void)n_in; (void)out_size; (void)ws_size;
  const float* x = (const float*)d_in[0];
  const float* w_qkv = (const float*)d_in[1];
  const float* b_qkv = (const float*)d_in[2];
  const float* w_o = (const float*)d_in[3];
  const float* b_o = (const float*)d_in[4];

  float* out = (float*)d_out;
  float* q = out + 4194304;
  float* k = q + 4194304;
  float* v = k + 4194304;

  float* qwin = (float*)d_ws;                 // 512*128 f32
  float* kwin = qwin + 65536;                 // 512*128 f32
  short* wpk_qkv = (short*)(kwin + 65536);    // 96 KB
  short* wpk_o = wpk_qkv + 49152;             // 32 KB
  short* vt = wpk_o + 16384;                  // 8 MB
  short* kbh = vt + 4194304;                  // 8 MB
  short* qbh = kbh + 4194304;                 // 8 MB

  k_pack2<<<128, 64, 0, stream>>>(w_qkv, w_o, wpk_qkv, wpk_o);
  k_qkv<<<512, 512, 0, stream>>>(x, wpk_qkv, b_qkv, w_qkv, q, k, v, vt, kbh, qbh, qwin, kwin);
  k_attn<<<512, 512, 0, stream>>>(qbh, kbh, vt, qwin, kwin, wpk_o, b_o, out);
}